// Round 4
// baseline (252.151 us; speedup 1.0000x reference)
//
#include <hip/hip_runtime.h>
#include <math.h>

// Problem constants
#define NB 2
#define CIN 16
#define COUT 8
#define DD 96
#define TDIM 256
#define NE 8
#define VOX (DD*DD*DD)          // 884736
#define OUT_ELEMS (NB*COUT*VOX) // 14155776

// conv LDS: ring of 5 halo planes, 18x18 each, [vox][8ci] f16 two halves
#define LX 18
#define PLANE (LX*LX)           // 324
#define RING 5
#define NVX (PLANE*RING)        // 1620
#define HALFB (NVX*16)          // 25920 B per ci-half
#define ZCH 12                  // z-outputs per block
#define NZB (DD/ZCH)            // 8

#define NTB3 (VOX/512)          // 1728 transpose blocks (2 voxels/thread)
#define MWN (COUT*CIN*27)       // 3456 mixed weights per batch

typedef _Float16 f16x8 __attribute__((ext_vector_type(8)));
typedef float f32x4 __attribute__((ext_vector_type(4)));

// ---------------- pure register transpose: x f32 [b][ci][vox] -> xt f16 [b][vox][ci16] ----------------
__global__ __launch_bounds__(256) void transpose_k(
    const float* __restrict__ x, _Float16* __restrict__ xt)
{
    const int t = threadIdx.x;
    const int b = blockIdx.y;
    const int vh = blockIdx.x * 256 + t;          // voxel-pair index
    const float* __restrict__ xb = x + (size_t)b * CIN * VOX;

    float2 f[CIN];
    #pragma unroll
    for (int ci = 0; ci < CIN; ++ci)
        f[ci] = ((const float2*)(xb + (size_t)ci * VOX))[vh];

    union { _Float16 h[16]; uint4 u[2]; } o0, o1;
    #pragma unroll
    for (int ci = 0; ci < CIN; ++ci) {
        o0.h[ci] = (_Float16)f[ci].x;
        o1.h[ci] = (_Float16)f[ci].y;
    }
    uint4* __restrict__ dst = (uint4*)(xt + (size_t)b * VOX * 16) + (size_t)vh * 4;
    dst[0] = o0.u[0];
    dst[1] = o0.u[1];
    dst[2] = o1.u[0];
    dst[3] = o1.u[1];
}

// ---------------- conv: inline setup + ring-z implicit-GEMM f16 MFMA ----------------
// Block = 256 thr (4 waves). Grid = (36, 8, 2). Each block: 16x * 16y * 12z outputs.
__global__ __launch_bounds__(256, 3) void conv_mfma(
    const _Float16* __restrict__ xt,   // [b][vox][16] f16
    const float* __restrict__ text,
    const float* __restrict__ wb,    // [E,COUT,CIN,27]
    const float* __restrict__ bb,    // [E,COUT]
    const float* __restrict__ rw1, const float* __restrict__ rb1,
    const float* __restrict__ rw2, const float* __restrict__ rb2,
    const float* __restrict__ mw1, const float* __restrict__ mb1,
    const float* __restrict__ mw2, const float* __restrict__ mb2,
    float* __restrict__ dout_tail,   // d_out + OUT_ELEMS
    float* __restrict__ out)
{
    __shared__ char lds[2*HALFB];   // 51840 B; setup scratch time-shares the front
    const int tid  = threadIdx.x;
    const int lane = tid & 63;
    const int wv   = tid >> 6;
    const int b    = blockIdx.z;
    const int zb   = blockIdx.y * ZCH;
    const int xti  = blockIdx.x % 6;
    const int yti  = blockIdx.x / 6;
    const int x0   = xti * 16, y0 = yti * 16;
    const bool wr  = (blockIdx.x == 0) && (blockIdx.y == 0);  // logits writer

    // setup scratch aliases (first 15.5 KB of lds, dead before staging)
    float* smw   = (float*)lds;               // [3456]
    float* spart = (float*)(lds + 13824);     // [256]
    float* shg   = (float*)(lds + 14848);     // [128] (router 0..63, mod 64..127)
    float* slog  = (float*)(lds + 15360);     // [8]
    float* srwv  = (float*)(lds + 15392);     // [8]
    float* sa    = (float*)(lds + 15424);     // [8]
    float* sd    = (float*)(lds + 15456);     // [8]

    // ---- inline setup: layer-1 MLPs (128 dots of 256, k-split x2, 4 accs) ----
    {
        const int o = tid & 127, which = o >> 6, j = o & 63, kh = tid >> 7;
        const float* __restrict__ w1 = which ? mw1 : rw1;
        const float* __restrict__ tx = text + b*TDIM + kh*128;
        const float* __restrict__ wp = w1 + (size_t)(kh*128)*64 + j;
        float a0=0.f, a1=0.f, a2=0.f, a3=0.f;
        #pragma unroll 8
        for (int k = 0; k < 128; k += 4) {
            a0 = fmaf(tx[k+0], wp[(k+0)*64], a0);
            a1 = fmaf(tx[k+1], wp[(k+1)*64], a1);
            a2 = fmaf(tx[k+2], wp[(k+2)*64], a2);
            a3 = fmaf(tx[k+3], wp[(k+3)*64], a3);
        }
        spart[tid] = (a0 + a1) + (a2 + a3);
    }
    __syncthreads();
    if (tid < 128) {
        const int which = tid >> 6, j = tid & 63;
        float acc = (which ? mb1 : rb1)[j] + spart[tid] + spart[tid + 128];
        shg[which*64 + j] = (acc >= 0.f) ? acc : 0.1f * acc;
    }
    __syncthreads();
    if (tid < NE) {
        float acc = rb2[tid];
        #pragma unroll
        for (int k = 0; k < 64; ++k) acc = fmaf(shg[k], rw2[k*NE + tid], acc);
        slog[tid] = acc;
        if (wr) dout_tail[b*NE + tid] = acc;          // router_logits
    }
    __syncthreads();
    if (tid < NE) {
        float mx = slog[0];
        for (int k = 1; k < NE; ++k) mx = fmaxf(mx, slog[k]);
        float ssum = 0.f;
        for (int k = 0; k < NE; ++k) ssum += expf(slog[k] - mx);
        const float w = expf(slog[tid] - mx) / ssum;
        srwv[tid] = w;
        if (wr) dout_tail[NB*NE + b*NE + tid] = w;    // routing_weights
    }
    __syncthreads();
    float rv[NE];
    #pragma unroll
    for (int e = 0; e < NE; ++e) rv[e] = srwv[e];
    if (tid < COUT) {
        float acc = mb2[tid];
        #pragma unroll
        for (int k = 0; k < 64; ++k) acc = fmaf(shg[64 + k], mw2[k*COUT + tid], acc);
        const float gamma = 1.f / (1.f + expf(-acc));
        const float a = 1.f + gamma;
        float cb = 0.f;
        #pragma unroll
        for (int e = 0; e < NE; ++e) cb = fmaf(rv[e], bb[e*COUT + tid], cb);
        sa[tid] = a;
        sd[tid] = cb * a;
    }
    // mix expert basis (coalesced; identical values in every block)
    #pragma unroll
    for (int i0 = 0; i0 < (MWN + 255)/256; ++i0) {
        const int i = i0*256 + tid;
        if (i < MWN) {
            float v = 0.f;
            #pragma unroll
            for (int e = 0; e < NE; ++e) v = fmaf(rv[e], wb[e*MWN + i], v);
            smw[i] = v;
        }
    }
    __syncthreads();

    // ---- bake per-lane B fragments from LDS mw ----
    const int q = lane >> 4, m = lane & 15, pbit = q & 1, hbit = q >> 1;
    f16x8 bfrag[14];
    {
        const int cib = (q >> 1) * 8;
        #pragma unroll
        for (int c = 0; c < 14; ++c) {
            int tap;
            if (c < 9)        tap = (c/3)*9 + (c%3)*3 + pbit;
            else if (c < 12)  tap = (c-9)*9 + pbit*3 + 2;
            else if (c == 12) tap = pbit*9 + 8;
            else              tap = pbit ? -1 : 26;
            f16x8 v;
            #pragma unroll
            for (int j = 0; j < 8; ++j) v[j] = (_Float16)0.f;
            if (m < 8 && tap >= 0) {
                const float* mr = smw + (m*CIN + cib)*27 + tap;
                #pragma unroll
                for (int j = 0; j < 8; ++j) v[j] = (_Float16)mr[j*27];
            }
            bfrag[c] = v;
        }
    }
    const float a_n = sa[m & 7];
    const float d_n = sd[m & 7];
    __syncthreads();   // all setup LDS reads done before staging overwrites

    // ---- staging geometry: thread owns plane slots s=tid (and tid+256 if <324) ----
    const _Float16* __restrict__ xtb = xt + (size_t)b * VOX * 16;
    const int lyA = tid / LX, lxA = tid - lyA*LX;
    const int ygA = y0 - 1 + lyA, xgA = x0 - 1 + lxA;
    const bool okA = ((unsigned)ygA < 96u) & ((unsigned)xgA < 96u);
    const int pvA = ygA*DD + xgA;
    const int sB  = tid + 256;
    const bool hasB = sB < PLANE;                 // tid < 68
    const int lyB = sB / LX, lxB = sB - lyB*LX;
    const int ygB = y0 - 1 + lyB, xgB = x0 - 1 + lxB;
    const bool okB = hasB && (((unsigned)ygB < 96u) & ((unsigned)xgB < 96u));
    const int pvB = ygB*DD + xgB;

    // prologue: planes z = zb-1 .. zb+2 into ring slots 0..3
    #pragma unroll
    for (int lp = 0; lp < 4; ++lp) {
        const int zg = zb - 1 + lp;
        const bool zok = (unsigned)zg < 96u;
        uint4 l0 = make_uint4(0,0,0,0), h0 = l0, l1 = l0, h1 = l0;
        if (okA && zok) { const uint4* p = (const uint4*)(xtb + ((size_t)zg*(DD*DD) + pvA)*16); l0 = p[0]; h0 = p[1]; }
        if (okB && zok) { const uint4* p = (const uint4*)(xtb + ((size_t)zg*(DD*DD) + pvB)*16); l1 = p[0]; h1 = p[1]; }
        *(uint4*)&lds[(lp*PLANE + tid)*16]          = l0;
        *(uint4*)&lds[HALFB + (lp*PLANE + tid)*16]  = h0;
        if (hasB) {
            *(uint4*)&lds[(lp*PLANE + sB)*16]         = l1;
            *(uint4*)&lds[HALFB + (lp*PLANE + sB)*16] = h1;
        }
    }
    __syncthreads();

    const int com = hbit*HALFB + m*16;
    const int dA = pbit*16;          // dx parity
    const int dB = pbit*(LX*16);     // dy parity (288)

    #define LDV(sl_, vo_, dd_) (*(const f16x8*)&lds[((sl_)*PLANE + (vo_))*16 + com + (dd_)])

    for (int zo = 0; zo < ZCH; ++zo) {
        // issue prefetch loads for plane lp = zo+4 (z = zb+zo+3); write after compute
        const bool st = (zo <= ZCH-3);
        const int zgs = zb + zo + 3;
        uint4 l0 = make_uint4(0,0,0,0), h0 = l0, l1 = l0, h1 = l0;
        if (st) {
            const bool zok = (unsigned)zgs < 96u;
            if (okA && zok) { const uint4* p = (const uint4*)(xtb + ((size_t)zgs*(DD*DD) + pvA)*16); l0 = p[0]; h0 = p[1]; }
            if (okB && zok) { const uint4* p = (const uint4*)(xtb + ((size_t)zgs*(DD*DD) + pvB)*16); l1 = p[0]; h1 = p[1]; }
        }

        const int s_0 = zo % RING, s_1 = (zo+1) % RING, s_2 = (zo+2) % RING;
        const int sH12 = pbit ? s_1 : s_0;
        const int sl0 = s_0, sl1 = s_1, sl2 = s_2;

        #pragma unroll
        for (int yi4 = 0; yi4 < 4; ++yi4) {
            const int yi = wv*4 + yi4;
            const f16x8 A00 = LDV(sl0, (yi+0)*LX, dA), A01 = LDV(sl0, (yi+1)*LX, dA), A02 = LDV(sl0, (yi+2)*LX, dA);
            const f16x8 A10 = LDV(sl1, (yi+0)*LX, dA), A11 = LDV(sl1, (yi+1)*LX, dA), A12 = LDV(sl1, (yi+2)*LX, dA);
            const f16x8 A20 = LDV(sl2, (yi+0)*LX, dA), A21 = LDV(sl2, (yi+1)*LX, dA), A22 = LDV(sl2, (yi+2)*LX, dA);
            const f16x8 G0  = LDV(sl0, yi*LX + 2, dB), G1  = LDV(sl1, yi*LX + 2, dB), G2  = LDV(sl2, yi*LX + 2, dB);
            const f16x8 H12v = LDV(sH12, (yi+2)*LX + 2, 0);
            const f16x8 H13v = LDV(sl2,  (yi+2)*LX + 2, 0);   // odd-parity lanes alias (B=0 there)

            f32x4 acc0 = {0.f,0.f,0.f,0.f}, acc1 = {0.f,0.f,0.f,0.f};
            acc0 = __builtin_amdgcn_mfma_f32_16x16x32_f16(A00,  bfrag[0],  acc0, 0,0,0);
            acc1 = __builtin_amdgcn_mfma_f32_16x16x32_f16(A01,  bfrag[1],  acc1, 0,0,0);
            acc0 = __builtin_amdgcn_mfma_f32_16x16x32_f16(A02,  bfrag[2],  acc0, 0,0,0);
            acc1 = __builtin_amdgcn_mfma_f32_16x16x32_f16(A10,  bfrag[3],  acc1, 0,0,0);
            acc0 = __builtin_amdgcn_mfma_f32_16x16x32_f16(A11,  bfrag[4],  acc0, 0,0,0);
            acc1 = __builtin_amdgcn_mfma_f32_16x16x32_f16(A12,  bfrag[5],  acc1, 0,0,0);
            acc0 = __builtin_amdgcn_mfma_f32_16x16x32_f16(A20,  bfrag[6],  acc0, 0,0,0);
            acc1 = __builtin_amdgcn_mfma_f32_16x16x32_f16(A21,  bfrag[7],  acc1, 0,0,0);
            acc0 = __builtin_amdgcn_mfma_f32_16x16x32_f16(A22,  bfrag[8],  acc0, 0,0,0);
            acc1 = __builtin_amdgcn_mfma_f32_16x16x32_f16(G0,   bfrag[9],  acc1, 0,0,0);
            acc0 = __builtin_amdgcn_mfma_f32_16x16x32_f16(G1,   bfrag[10], acc0, 0,0,0);
            acc1 = __builtin_amdgcn_mfma_f32_16x16x32_f16(G2,   bfrag[11], acc1, 0,0,0);
            acc0 = __builtin_amdgcn_mfma_f32_16x16x32_f16(H12v, bfrag[12], acc0, 0,0,0);
            acc1 = __builtin_amdgcn_mfma_f32_16x16x32_f16(H13v, bfrag[13], acc1, 0,0,0);

            if (m < 8) {  // D cols 8..15 are padding
                const int zz = zb + zo, yy = y0 + yi;
                float* __restrict__ op = out + (size_t)(b*COUT + m)*VOX
                                            + (size_t)(zz*DD + yy)*DD + x0 + q*4;
                f32x4 res;
                #pragma unroll
                for (int r = 0; r < 4; ++r) res[r] = fmaf(acc0[r] + acc1[r], a_n, d_n);
                *reinterpret_cast<f32x4*>(op) = res;
            }
        }

        // write staged plane (slot (zo+4)%5 == (zo-1)%5: out of current window, last read 2 barriers ago)
        if (st) {
            const int sls = (zo+4) % RING;
            *(uint4*)&lds[(sls*PLANE + tid)*16]          = l0;
            *(uint4*)&lds[HALFB + (sls*PLANE + tid)*16]  = h0;
            if (hasB) {
                *(uint4*)&lds[(sls*PLANE + sB)*16]         = l1;
                *(uint4*)&lds[HALFB + (sls*PLANE + sB)*16] = h1;
            }
        }
        __syncthreads();
    }
    #undef LDV
}

extern "C" void kernel_launch(void* const* d_in, const int* in_sizes, int n_in,
                              void* d_out, int out_size, void* d_ws, size_t ws_size,
                              hipStream_t stream) {
    const float* x    = (const float*)d_in[0];
    const float* text = (const float*)d_in[1];
    const float* wb   = (const float*)d_in[2];
    const float* bb   = (const float*)d_in[3];
    const float* rw1  = (const float*)d_in[4];
    const float* rb1  = (const float*)d_in[5];
    const float* rw2  = (const float*)d_in[6];
    const float* rb2  = (const float*)d_in[7];
    const float* mw1  = (const float*)d_in[8];
    const float* mb1  = (const float*)d_in[9];
    const float* mw2  = (const float*)d_in[10];
    const float* mb2  = (const float*)d_in[11];

    float* out = (float*)d_out;
    _Float16* xt = (_Float16*)d_ws;

    transpose_k<<<dim3(NTB3, NB), 256, 0, stream>>>(x, xt);

    conv_mfma<<<dim3(36, NZB, NB), 256, 0, stream>>>(
        xt, text, wb, bb, rw1, rb1, rw2, rb2, mw1, mb1, mw2, mb2,
        out + OUT_ELEMS, out);
}